// Round 6
// baseline (178.505 us; speedup 1.0000x reference)
//
#include <hip/hip_runtime.h>
#include <cstdint>

#define EPSF 1e-6f
#define P 72          // LDS row stride in bf16 (36 dwords -> 2-way/free on b128 frags)

typedef __bf16 bf16x8 __attribute__((ext_vector_type(8)));
typedef float floatx4 __attribute__((ext_vector_type(4)));
typedef unsigned short ushortx8 __attribute__((ext_vector_type(8)));
typedef unsigned short ushortx4 __attribute__((ext_vector_type(4)));
typedef unsigned short ushortx2 __attribute__((ext_vector_type(2)));

static __device__ __forceinline__ float fmap(float x){ return x > 0.f ? x + 1.f : __expf(x); }
static __device__ __forceinline__ unsigned short f2bf(float f){
    unsigned u = __builtin_bit_cast(unsigned, f);
    u += 0x7fffu + ((u >> 16) & 1u);
    return (unsigned short)(u >> 16);
}
static __device__ __forceinline__ bf16x8 ldf(const unsigned short* p){
    return __builtin_bit_cast(bf16x8, *(const ushortx8*)p);
}

// One block per (b, h, m-quarter). Walks 32 chunks of 64 tokens; scan state S
// lives in fp32 MFMA accumulators (wave w owns d-cols [16w,16w+16)), bf16 image
// Sb double-buffered for GEMM2 B-frags. Kprefix in registers + kf-tile row 64.
__global__ __launch_bounds__(256, 1) void fused(
    const float* __restrict__ qp, const float* __restrict__ kp,
    const float* __restrict__ vp, float* __restrict__ outp)
{
    __shared__ __align__(16) unsigned short qf [2][64*P];  // [l][d]; scores overlay own rows
    __shared__ __align__(16) unsigned short kf [2][80*P];  // [s][d]; row64=Kp, 65-79=0
    __shared__ __align__(16) unsigned short kft[2][64*P];  // kf^T [d][s]
    __shared__ __align__(16) unsigned short vt [2][16*P];  // v^T m-slice [m][s]
    __shared__ __align__(16) unsigned short Sb [2][16*P];  // S^T bf16 [m][d]
    const int ci = blockIdx.x;
    const int bh = ci >> 2, mq = ci & 3;
    const int b = bh >> 4, h = bh & 15;
    const int t = threadIdx.x;
    const int w = t >> 6, lane = t & 63, quad = lane >> 4, lr = lane & 15;
    const int64_t gbh = ((int64_t)b*2048*16 + (int64_t)h)*64;

    float4 R[9];   // prefetch: q 4, k 4, v 1

    auto issue = [&](int c) {
        const int64_t g = gbh + (int64_t)c*65536;
#pragma unroll
        for (int i = 0; i < 2; ++i) {
            int flat = t + 256*i, l0 = (flat >> 4)*2, col = (flat & 15)*4;
            const float* gq = qp + g + (int64_t)l0*1024 + col;
            const float* gk = kp + g + (int64_t)l0*1024 + col;
            R[i*2+0] = *(const float4*)(gq);
            R[i*2+1] = *(const float4*)(gq + 1024);
            R[4+i*2+0] = *(const float4*)(gk);
            R[4+i*2+1] = *(const float4*)(gk + 1024);
        }
        R[8] = *(const float4*)(vp + g + (int64_t)(t >> 2)*1024 + mq*16 + (t & 3)*4);
    };
    auto stage = [&](int buf) {
#pragma unroll
        for (int i = 0; i < 2; ++i) {
            int flat = t + 256*i, l0 = (flat >> 4)*2, col = (flat & 15)*4;
            float4 qa = R[i*2+0], qb = R[i*2+1], ka = R[4+i*2+0], kb = R[4+i*2+1];
            ushortx4 qra = { f2bf(fmap(qa.x)), f2bf(fmap(qa.y)), f2bf(fmap(qa.z)), f2bf(fmap(qa.w)) };
            ushortx4 qrb = { f2bf(fmap(qb.x)), f2bf(fmap(qb.y)), f2bf(fmap(qb.z)), f2bf(fmap(qb.w)) };
            ushortx4 kra = { f2bf(fmap(ka.x)), f2bf(fmap(ka.y)), f2bf(fmap(ka.z)), f2bf(fmap(ka.w)) };
            ushortx4 krb = { f2bf(fmap(kb.x)), f2bf(fmap(kb.y)), f2bf(fmap(kb.z)), f2bf(fmap(kb.w)) };
            *(ushortx4*)(qf[buf] + l0*P + col)     = qra;
            *(ushortx4*)(qf[buf] + (l0+1)*P + col) = qrb;
            *(ushortx4*)(kf[buf] + l0*P + col)     = kra;
            *(ushortx4*)(kf[buf] + (l0+1)*P + col) = krb;
#pragma unroll
            for (int e = 0; e < 4; ++e)
                *(ushortx2*)(kft[buf] + (col+e)*P + l0) = ushortx2{ kra[e], krb[e] };
        }
        {
            int l = t >> 2, m0 = (t & 3)*4;
            float vv[4] = { R[8].x, R[8].y, R[8].z, R[8].w };
#pragma unroll
            for (int e = 0; e < 4; ++e)
                vt[buf][(m0+e)*P + l] = f2bf(vv[e]);
        }
    };

    issue(0);
    if (t < 144) {   // zero kf rows 64-79 (both bufs) and Sb[0]
        ushortx8 z8 = {0,0,0,0,0,0,0,0};
        *(ushortx8*)(kf[0] + 64*P + t*8) = z8;
        *(ushortx8*)(kf[1] + 64*P + t*8) = z8;
        *(ushortx8*)(Sb[0] + t*8) = z8;
    }
    stage(0);
    __syncthreads();

    floatx4 accS = {0.f,0.f,0.f,0.f};   // S^T[d=16w+quad*4+r][m=lr], fp32 running prefix
    float kpr = 0.f;                     // Kprefix[16w+lr] (consistent across quads)
    const ushortx8 ou = {0x3F80,0x3F80,0x3F80,0x3F80,0x3F80,0x3F80,0x3F80,0x3F80};
    const bf16x8 ones = __builtin_bit_cast(bf16x8, ou);
    const int l0 = 16*w;

#pragma unroll 1
    for (int c = 0; c < 32; ++c) {
        const int cur = c & 1, nxt = cur ^ 1;
        if (c < 31) issue(c+1);

        // GEMM1: scores = qf·kf^T (tiles 0-3) + z-prefix column (tile 4)
        bf16x8 aq0 = ldf(qf[cur] + (l0+lr)*P + quad*8);
        bf16x8 aq1 = ldf(qf[cur] + (l0+lr)*P + 32 + quad*8);
        floatx4 sc[5];
#pragma unroll
        for (int tt = 0; tt < 5; ++tt) sc[tt] = floatx4{0.f,0.f,0.f,0.f};
#pragma unroll
        for (int tt = 0; tt < 5; ++tt) {
            bf16x8 b0 = ldf(kf[cur] + (tt*16+lr)*P + quad*8);
            bf16x8 b1 = ldf(kf[cur] + (tt*16+lr)*P + 32 + quad*8);
            sc[tt] = __builtin_amdgcn_mfma_f32_16x16x32_bf16(aq0, b0, sc[tt], 0, 0, 0);
            sc[tt] = __builtin_amdgcn_mfma_f32_16x16x32_bf16(aq1, b1, sc[tt], 0, 0, 0);
        }
        // causal mask + z row-sums + overlay masked scores onto own qf rows
        float zp[4] = {0.f,0.f,0.f,0.f};
#pragma unroll
        for (int tt = 0; tt < 4; ++tt)
#pragma unroll
            for (int r = 0; r < 4; ++r) {
                int row = l0 + quad*4 + r, col = tt*16 + lr;
                float val = (col <= row) ? sc[tt][r] : 0.f;
                zp[r] += val;
                qf[cur][row*P + col] = f2bf(val);
            }
#pragma unroll
        for (int r = 0; r < 4; ++r) zp[r] += (lr == 0) ? sc[4][r] : 0.f;
#pragma unroll
        for (int m = 1; m < 16; m <<= 1)
#pragma unroll
            for (int r = 0; r < 4; ++r) zp[r] += __shfl_xor(zp[r], m, 64);
        float rz[4];
#pragma unroll
        for (int r = 0; r < 4; ++r) rz[r] = 1.f / (zp[r] + EPSF);

        // GEMM2: out[l-tile][m16] = Amask·v + qf·S_prefix
        bf16x8 a20 = ldf(qf[cur] + (l0+lr)*P + quad*8);          // own-row overlay (intra-wave RAW)
        bf16x8 a21 = ldf(qf[cur] + (l0+lr)*P + 32 + quad*8);
        bf16x8 bv0 = ldf(vt[cur] + lr*P + quad*8);
        bf16x8 bv1 = ldf(vt[cur] + lr*P + 32 + quad*8);
        bf16x8 bS0 = ldf(Sb[cur] + lr*P + quad*8);
        bf16x8 bS1 = ldf(Sb[cur] + lr*P + 32 + quad*8);
        floatx4 oa = {0.f,0.f,0.f,0.f};
        oa = __builtin_amdgcn_mfma_f32_16x16x32_bf16(a20, bv0, oa, 0, 0, 0);
        oa = __builtin_amdgcn_mfma_f32_16x16x32_bf16(a21, bv1, oa, 0, 0, 0);
        oa = __builtin_amdgcn_mfma_f32_16x16x32_bf16(aq0, bS0, oa, 0, 0, 0);
        oa = __builtin_amdgcn_mfma_f32_16x16x32_bf16(aq1, bS1, oa, 0, 0, 0);
        {
            const int64_t go = gbh + (int64_t)c*65536 + mq*16 + lr;
#pragma unroll
            for (int r = 0; r < 4; ++r)
                outp[go + (int64_t)(l0 + quad*4 + r)*1024] = oa[r] * rz[r];
        }

        // state update: accS += kf^T · v^T  (wave w owns d-cols [16w,16w+16))
        bf16x8 t0 = ldf(kft[cur] + (l0+lr)*P + quad*8);
        bf16x8 t1 = ldf(kft[cur] + (l0+lr)*P + 32 + quad*8);
        accS = __builtin_amdgcn_mfma_f32_16x16x32_bf16(t0, bv0, accS, 0, 0, 0);
        accS = __builtin_amdgcn_mfma_f32_16x16x32_bf16(t1, bv1, accS, 0, 0, 0);
#pragma unroll
        for (int r = 0; r < 4; ++r)
            Sb[nxt][lr*P + l0 + quad*4 + r] = f2bf(accS[r]);

        // Kprefix update via ones-MFMA column sum of kf^T; write row 64 of next kf
        floatx4 colc = {0.f,0.f,0.f,0.f};
        colc = __builtin_amdgcn_mfma_f32_16x16x32_bf16(ones, t0, colc, 0, 0, 0);
        colc = __builtin_amdgcn_mfma_f32_16x16x32_bf16(ones, t1, colc, 0, 0, 0);
        kpr += colc[0];                      // all quads hold same value for d=16w+lr
        if (quad == 0) kf[nxt][64*P + l0 + lr] = f2bf(kpr);

        if (c < 31) stage(nxt);
        __syncthreads();
    }
}

extern "C" void kernel_launch(void* const* d_in, const int* in_sizes, int n_in,
                              void* d_out, int out_size, void* d_ws, size_t ws_size,
                              hipStream_t stream) {
    const float* q = (const float*)d_in[0];
    const float* k = (const float*)d_in[1];
    const float* v = (const float*)d_in[2];
    float* out = (float*)d_out;
    fused<<<256, 256, 0, stream>>>(q, k, v, out);
}